// Round 4
// baseline (86.423 us; speedup 1.0000x reference)
//
#include <hip/hip_runtime.h>
#include <math.h>

#define NG 1024
#define NSEG 8
#define SEG_LEN 128            // gaussians per wave segment
#define PX_PER_BLOCK 128       // 512 threads, 2 px per thread
#define IMG_W 256
#define IMG_H 256
#define JITTER 1e-6f
#define L2E 1.4426950408889634f

__device__ __forceinline__ float fexp2(float x)  { return __builtin_amdgcn_exp2f(x); }
__device__ __forceinline__ float frcp(float x)   { return __builtin_amdgcn_rcpf(x); }
__device__ __forceinline__ float fexp(float x)   { return fexp2(x * L2E); }
__device__ __forceinline__ float fsigmoid(float x) { return frcp(1.0f + fexp(-x)); }
__device__ __forceinline__ float ftanh(float x) {
    float t = fexp2(2.0f * L2E * x);      // exp(2x)
    return 1.0f - 2.0f * frcp(t + 1.0f);
}
__device__ __forceinline__ float rdlane(float v, int lane) {
    return __int_as_float(__builtin_amdgcn_readlane(__float_as_int(v), lane));
}

struct GP { float mx, my, A, B, D, op; };

// Compute activation + inverse-covariance params for gaussian g (per lane).
__device__ __forceinline__ GP compute_params(int g,
                                             const float* __restrict__ means,
                                             const float* __restrict__ scales,
                                             const float* __restrict__ thetas,
                                             const float* __restrict__ opacities) {
    GP p;
    p.mx = ftanh(means[2 * g]);
    p.my = ftanh(means[2 * g + 1]);
    float s2x = fexp(2.0f * scales[2 * g]);       // exp(scales)^2
    float s2y = fexp(2.0f * scales[2 * g + 1]);
    // theta = sigmoid(t)*2pi; v_sin/cos take revolutions -> feed sigmoid raw.
    float rev = fsigmoid(thetas[g]);
    float si = __builtin_amdgcn_sinf(rev);
    float c  = __builtin_amdgcn_cosf(rev);
    float a = c * c * s2x + si * si * s2y + JITTER;
    float b = c * si * (s2x - s2y);
    float d = si * si * s2x + c * c * s2y + JITTER;
    float inv_det = frcp(a * d - b * b);
    // alpha = op * exp2(A*dx^2 + B*dx*dy + D*dy^2)
    p.A = -0.5f * L2E * d * inv_det;
    p.B =  L2E * b * inv_det;        // -L2E * (-b/det)
    p.D = -0.5f * L2E * a * inv_det;
    p.op = fsigmoid(opacities[g]);
    return p;
}

// One fused kernel. Block = 512 threads = 8 waves, handles 128 pixels.
// Wave w owns gaussian segment [w*128,(w+1)*128): lane l precomputes params
// for gaussians w*128+l and w*128+64+l (registers), then the wave composites
// its segment over the block's 128 pixels (2 per lane) using v_readlane
// broadcasts (uniform dynamic lane index). Segments combine in order via LDS.
__global__ __launch_bounds__(512, 4)
void gs_fused(const float* __restrict__ means,
              const float* __restrict__ scales,
              const float* __restrict__ thetas,
              const float* __restrict__ opacities,
              float* __restrict__ out) {
    __shared__ float2 seg_res[NSEG][PX_PER_BLOCK];

    int tid  = threadIdx.x;
    int lane = tid & 63;
    int seg  = __builtin_amdgcn_readfirstlane(tid >> 6);

    // ---- Phase 1: per-wave param precompute (lane-parallel) ----
    int g0 = seg * SEG_LEN + lane;
    GP q0 = compute_params(g0,      means, scales, thetas, opacities);
    GP q1 = compute_params(g0 + 64, means, scales, thetas, opacities);

    // ---- Phase 2: composite this wave's segment over 128 pixels ----
    int pbase = blockIdx.x * PX_PER_BLOCK;
    int p0 = pbase + lane;
    int p1 = p0 + 64;
    const float step = 2.0f / 255.0f;              // linspace(-1,1,256)
    float x0 = fmaf((float)(p0 & 255), step, -1.0f);
    float y0 = fmaf((float)(p0 >> 8),  step, -1.0f);
    float x1 = fmaf((float)(p1 & 255), step, -1.0f);
    float y1 = fmaf((float)(p1 >> 8),  step, -1.0f);

    float acc0 = 0.0f, T0 = 1.0f, acc1 = 0.0f, T1 = 1.0f;

    #pragma unroll 8
    for (int g = 0; g < 64; ++g) {
        float mx = rdlane(q0.mx, g), my = rdlane(q0.my, g);
        float A  = rdlane(q0.A,  g), B  = rdlane(q0.B,  g);
        float D  = rdlane(q0.D,  g), op = rdlane(q0.op, g);
        float dx = x0 - mx, dy = y0 - my;
        float e2 = fmaf(dx, fmaf(A, dx, B * dy), D * (dy * dy));
        float al = op * fexp2(e2);
        acc0 = fmaf(al, T0, acc0);  T0 = fmaf(-al, T0, T0);
        dx = x1 - mx; dy = y1 - my;
        e2 = fmaf(dx, fmaf(A, dx, B * dy), D * (dy * dy));
        al = op * fexp2(e2);
        acc1 = fmaf(al, T1, acc1);  T1 = fmaf(-al, T1, T1);
    }
    #pragma unroll 8
    for (int g = 0; g < 64; ++g) {
        float mx = rdlane(q1.mx, g), my = rdlane(q1.my, g);
        float A  = rdlane(q1.A,  g), B  = rdlane(q1.B,  g);
        float D  = rdlane(q1.D,  g), op = rdlane(q1.op, g);
        float dx = x0 - mx, dy = y0 - my;
        float e2 = fmaf(dx, fmaf(A, dx, B * dy), D * (dy * dy));
        float al = op * fexp2(e2);
        acc0 = fmaf(al, T0, acc0);  T0 = fmaf(-al, T0, T0);
        dx = x1 - mx; dy = y1 - my;
        e2 = fmaf(dx, fmaf(A, dx, B * dy), D * (dy * dy));
        al = op * fexp2(e2);
        acc1 = fmaf(al, T1, acc1);  T1 = fmaf(-al, T1, T1);
    }

    seg_res[seg][lane]      = make_float2(acc0, T0);
    seg_res[seg][lane + 64] = make_float2(acc1, T1);
    __syncthreads();

    // ---- Phase 3: in-order combine across segments, write out ----
    if (tid < PX_PER_BLOCK) {
        float A = 0.0f, T = 1.0f;
        #pragma unroll
        for (int s = 0; s < NSEG; ++s) {
            float2 v = seg_res[s][tid];
            A = fmaf(T, v.x, A);
            T *= v.y;
        }
        // bg = (0,0,0): all 3 channels = A
        float* o = out + 3 * (pbase + tid);
        o[0] = A;
        o[1] = A;
        o[2] = A;
    }
}

extern "C" void kernel_launch(void* const* d_in, const int* in_sizes, int n_in,
                              void* d_out, int out_size, void* d_ws, size_t ws_size,
                              hipStream_t stream) {
    const float* means     = (const float*)d_in[0];
    const float* scales    = (const float*)d_in[1];
    const float* thetas    = (const float*)d_in[2];
    const float* opacities = (const float*)d_in[3];
    float* out = (float*)d_out;

    gs_fused<<<dim3((IMG_W * IMG_H) / PX_PER_BLOCK), dim3(512), 0, stream>>>(
        means, scales, thetas, opacities, out);
}